// Round 13
// baseline (284.016 us; speedup 1.0000x reference)
//
#include <hip/hip_runtime.h>

typedef short  bf16x8 __attribute__((ext_vector_type(8)));
typedef float  f32x4  __attribute__((ext_vector_type(4)));
typedef unsigned u32x4 __attribute__((ext_vector_type(4)));

#define CC 8
#define NN 1024
#define TT 8
#define II 64
#define HH 4
#define FF 64
#define EE (CC*NN*16)          // 131072 edges
#define KK 256                 // F*H
#define MAXD 64                // CSR slot cap (P(indeg>64)≈0 at λ=16)

static const size_t OUT_ELEMS  = (size_t)CC*NN*TT*FF;     // 4,194,304
static const size_t ATTN_ELEMS = (size_t)CC*NN*NN*HH;     // 33,554,432

// ws layout (bytes); ADJ..DEG zeroed as one 2,129,920 B range (130 x 16 KB)
static const size_t PG_OFF   = 0;                          // Pg bf16 33,554,432
static const size_t ASRC_OFF = 33554432;                   // a_src f32 131,072
static const size_t ADST_OFF = ASRC_OFF + 131072;          // a_dst f32 131,072
static const size_t SOFF_OFF = ADST_OFF + 131072;          // soff  f32 131,072
static const size_t ADJ_OFF  = SOFF_OFF + 131072;          // adj bitset 1,048,576
static const size_t ADJT_OFF = ADJ_OFF + 1048576;          // adjT bitset 1,048,576
static const size_t DEG_OFF  = ADJT_OFF + 1048576;         // deg i32 32,768
static const size_t LIST_OFF = DEG_OFF + 32768;            // lists u16 1,048,576
static const size_t FCT_OFF  = LIST_OFF + 1048576;         // fcT bf16 262,144

static __device__ inline unsigned short f2bf(float x) {
    union { float f; unsigned u; } q; q.f = x;
    unsigned r = q.u + 0x7fffu + ((q.u >> 16) & 1u);   // RNE
    return (unsigned short)(r >> 16);
}
static __device__ inline float bf2f(unsigned short u) {
    return __uint_as_float(((unsigned)u) << 16);
}

// ---------------------------------------------------------------------------
// K0: zero adj+adjT+deg (130 x 16 KB) + fc->fcT transpose (32 blocks)
// ---------------------------------------------------------------------------
__global__ __launch_bounds__(256) void k0_prep(const float* __restrict__ fc,
                                               unsigned short* __restrict__ fcT,
                                               uint4* __restrict__ zbase) {
    int bx = blockIdx.x;
    int tid = threadIdx.x;
    if (bx < 130) {
        uint4 z = make_uint4(0u, 0u, 0u, 0u);
        uint4* p = zbase + (size_t)bx*1024;
        #pragma unroll
        for (int r = 0; r < 4; ++r) p[r*256 + tid] = z;
    } else {
        int b = bx - 130;                // 0..31
        int t = b >> 2, ib = (b & 3) << 4;
        __shared__ unsigned short ls[256][17];
        #pragma unroll
        for (int r = 0; r < 16; ++r)
            ls[tid][r] = f2bf(fc[(size_t)(t*64 + ib + r)*KK + tid]);  // coalesced
        __syncthreads();
        int ii = tid & 15, k0 = tid >> 4;
        #pragma unroll
        for (int it = 0; it < 16; ++it) {
            int k = it*16 + k0;
            fcT[(size_t)t*16384 + (size_t)k*64 + ib + ii] = ls[k][ii];
        }
    }
}

// ---------------------------------------------------------------------------
// K1 (fused, R7 layout): [0,1024) MFMA projection+logits; [1024,1536) CSR +
// adjT build; [1536,9728) NT dense zero-fill of attn output.
// ---------------------------------------------------------------------------
__global__ __launch_bounds__(256) void k1_mfma(const float* __restrict__ nf,
                                               const unsigned short* __restrict__ fcT,
                                               const float* __restrict__ avs,
                                               const float* __restrict__ avd,
                                               unsigned short* __restrict__ Pg,
                                               float* __restrict__ a_src,
                                               float* __restrict__ a_dst,
                                               const int* __restrict__ ei,
                                               unsigned* __restrict__ adj,
                                               unsigned* __restrict__ adjT,
                                               int* __restrict__ deg,
                                               unsigned short* __restrict__ lists,
                                               u32x4* __restrict__ attnz) {
    int bxg = blockIdx.x;
    int tid = threadIdx.x;

    if (bxg >= 1536) {                   // ---- attn zero-fill: 8192 x 16 KB
        u32x4 z = (u32x4)(0u);
        u32x4* p = attnz + (size_t)(bxg - 1536)*1024;
        #pragma unroll
        for (int r = 0; r < 4; ++r)
            __builtin_nontemporal_store(z, &p[r*256 + tid]);
        return;
    }
    if (bxg >= 1024) {                   // ---- CSR adjacency + adjT: 512 blocks
        int e = (bxg - 1024)*256 + tid;
        int s = ei[e];
        int d = ei[EE + e];
        int c = s >> 10, i = s & 1023, j = d & 1023;
        int cj = (c << 10) + j;
        atomicOr(&adjT[((size_t)((c << 10) + i))*32 + (j >> 5)], 1u << (j & 31));
        unsigned bit = 1u << (i & 31);
        unsigned old = atomicOr(&adj[(size_t)cj*32 + (i >> 5)], bit);
        if (!(old & bit)) {              // first inserter of this (i,j)
            int pos = atomicAdd(&deg[cj], 1);
            if (pos < MAXD) lists[(size_t)cj*MAXD + pos] = (unsigned short)i;
        }
        return;
    }

    // ---- MFMA projection (blocks 0..1023); c = bx&7 keeps XCD alignment
    __shared__ unsigned short stg[8*2048];
    __shared__ float avsL[2048];
    __shared__ float avdL[2048];
    int bx = bxg;
    int c = bx & 7, t = (bx >> 3) & 7, tile = bx >> 6;
    int w = tid >> 6, lane = tid & 63;
    int col = lane & 15, g = lane >> 4;

    for (int l = tid; l < 2048; l += 256) {
        int t2 = l & 7, cl = (l >> 3) & 15, ctl = (l >> 7) & 3, h = l >> 9;
        int si = h*512 + t2*64 + ctl*16 + cl;
        avsL[l] = avs[si];
        avdL[l] = avd[si];
    }

    int row = tile*64 + w*16 + col;
    const float* ap = nf + ((size_t)(c*NN + row)*TT + t)*II + g*8;
    bf16x8 afr[2];
    #pragma unroll
    for (int ks = 0; ks < 2; ++ks) {
        float4 x = *(const float4*)(ap + ks*32);
        float4 y = *(const float4*)(ap + ks*32 + 4);
        afr[ks][0] = (short)f2bf(x.x); afr[ks][1] = (short)f2bf(x.y);
        afr[ks][2] = (short)f2bf(x.z); afr[ks][3] = (short)f2bf(x.w);
        afr[ks][4] = (short)f2bf(y.x); afr[ks][5] = (short)f2bf(y.y);
        afr[ks][6] = (short)f2bf(y.z); afr[ks][7] = (short)f2bf(y.w);
    }

    const unsigned short* bp = fcT + (size_t)t*256*64 + col*64 + g*8;
    f32x4 acc[16];
    #pragma unroll
    for (int ct = 0; ct < 16; ++ct) {
        bf16x8 b0 = *(const bf16x8*)(bp + (size_t)ct*16*64);
        bf16x8 b1 = *(const bf16x8*)(bp + (size_t)ct*16*64 + 32);
        f32x4 a; a[0] = 0.f; a[1] = 0.f; a[2] = 0.f; a[3] = 0.f;
        a = __builtin_amdgcn_mfma_f32_16x16x32_bf16(afr[0], b0, a, 0, 0, 0);
        a = __builtin_amdgcn_mfma_f32_16x16x32_bf16(afr[1], b1, a, 0, 0, 0);
        acc[ct] = a;
    }

    int nd = w*2 + (g >> 1);
    int t2b = (g & 1)*4;
    #pragma unroll
    for (int ctl = 0; ctl < 4; ++ctl) {
        int f2 = ctl*16 + col;
        #pragma unroll
        for (int v = 0; v < 4; ++v) {
            unsigned u0 = (unsigned)f2bf(acc[ctl     ][v]) | ((unsigned)f2bf(acc[ 4+ctl][v]) << 16);
            unsigned u1 = (unsigned)f2bf(acc[ 8+ctl][v]) | ((unsigned)f2bf(acc[12+ctl][v]) << 16);
            *(uint2*)&stg[nd*2048 + (t2b + v)*256 + f2*4] = make_uint2(u0, u1);
        }
    }

    __syncthreads();

    #pragma unroll
    for (int h = 0; h < 4; ++h) {
        float s = 0.f, d = 0.f;
        #pragma unroll
        for (int ctl = 0; ctl < 4; ++ctl) {
            float4 wS = *(const float4*)&avsL[((h*4 + ctl)*16 + col)*8 + t2b];
            float4 wD = *(const float4*)&avdL[((h*4 + ctl)*16 + col)*8 + t2b];
            f32x4 a = acc[h*4 + ctl];
            s += a[0]*wS.x + a[1]*wS.y + a[2]*wS.z + a[3]*wS.w;
            d += a[0]*wD.x + a[1]*wD.y + a[2]*wD.z + a[3]*wD.w;
        }
        #pragma unroll
        for (int m = 1; m <= 16; m <<= 1) { s += __shfl_xor(s, m); d += __shfl_xor(d, m); }
        if ((lane & 31) == 0) {
            int n2 = t*128 + tile*8 + w*2 + (lane >> 5);
            a_src[(size_t)(c*NN + n2)*HH + h] = s;
            a_dst[(size_t)(c*NN + n2)*HH + h] = d;
        }
    }

    {
        size_t gb = ((size_t)(c*NN) + t*128 + tile*8)*2048;
        const uint4* s4 = (const uint4*)stg;
        uint4* g4 = (uint4*)(Pg + gb);
        for (int l = tid; l < 2048; l += 256) g4[l] = s4[l];
    }
}

// ---------------------------------------------------------------------------
// K2: wave-per-dst softmax from CSR (no barriers): writes soff + attn scatter
// grid = 2048 blocks x 4 waves; block c = bx&7 (XCD-pinned)
// ---------------------------------------------------------------------------
__global__ __launch_bounds__(256) void k2_soft(const float* __restrict__ a_src,
                                               const float* __restrict__ a_dst,
                                               const int* __restrict__ deg,
                                               const unsigned short* __restrict__ lists,
                                               float* __restrict__ soff,
                                               float* __restrict__ attn_out) {
    int wid = threadIdx.x >> 6, lane = threadIdx.x & 63;
    int bx = blockIdx.x;
    int c = bx & 7;
    int j = (bx >> 3)*4 + wid;
    int cb = c << 10, cj = cb + j;

    int n = deg[cj]; if (n > MAXD) n = MAXD;
    bool valid = lane < n;
    int i = valid ? (int)lists[(size_t)cj*MAXD + lane] : 0;

    float4 ad = *(const float4*)&a_dst[(size_t)cj*4];
    float4 z4 = make_float4(-1e30f, -1e30f, -1e30f, -1e30f);
    if (valid) {
        float4 as = *(const float4*)&a_src[(size_t)(cb + i)*4];
        z4.x = as.x + ad.x; z4.x = (z4.x < 0.f) ? 0.2f*z4.x : z4.x;
        z4.y = as.y + ad.y; z4.y = (z4.y < 0.f) ? 0.2f*z4.y : z4.y;
        z4.z = as.z + ad.z; z4.z = (z4.z < 0.f) ? 0.2f*z4.z : z4.z;
        z4.w = as.w + ad.w; z4.w = (z4.w < 0.f) ? 0.2f*z4.w : z4.w;
    }
    float4 mx = z4;
    #pragma unroll
    for (int mm = 32; mm; mm >>= 1) {
        mx.x = fmaxf(mx.x, __shfl_xor(mx.x, mm));
        mx.y = fmaxf(mx.y, __shfl_xor(mx.y, mm));
        mx.z = fmaxf(mx.z, __shfl_xor(mx.z, mm));
        mx.w = fmaxf(mx.w, __shfl_xor(mx.w, mm));
    }
    float4 ez = make_float4(0.f, 0.f, 0.f, 0.f);
    if (valid) {
        ez.x = __expf(z4.x - mx.x);
        ez.y = __expf(z4.y - mx.y);
        ez.z = __expf(z4.z - mx.z);
        ez.w = __expf(z4.w - mx.w);
    }
    float4 sm = ez;
    #pragma unroll
    for (int mm = 32; mm; mm >>= 1) {
        sm.x += __shfl_xor(sm.x, mm);
        sm.y += __shfl_xor(sm.y, mm);
        sm.z += __shfl_xor(sm.z, mm);
        sm.w += __shfl_xor(sm.w, mm);
    }
    if (valid) {
        f32x4 sv;
        sv[0] = ez.x / sm.x; sv[1] = ez.y / sm.y;
        sv[2] = ez.z / sm.z; sv[3] = ez.w / sm.w;
        __builtin_nontemporal_store(sv,
            (f32x4*)&attn_out[((size_t)(cb + i)*NN + j)*4]);
    }
    if (lane == 0 && n > 0) {
        f32x4 so;
        so[0] = mx.x + __logf(sm.x); so[1] = mx.y + __logf(sm.y);
        so[2] = mx.z + __logf(sm.z); so[3] = mx.w + __logf(sm.w);
        *(f32x4*)&soff[(size_t)cj*4] = so;
    }
}

// ---------------------------------------------------------------------------
// K3: streaming PV with LDS accumulator tile. grid = (c, 32-j window, tf-half)
// = 512 blocks (c = bx&7). Block sweeps i=0..1023 in order; per i tests the
// 32-bit adjT window word; per hit recomputes w from soff and accumulates the
// head-mean dot into acc[jl][tid] (conflict-free). HBM: Pg streamed via L2.
// ---------------------------------------------------------------------------
__global__ __launch_bounds__(256) void k3_pv(const unsigned short* __restrict__ Pg,
                                             const float* __restrict__ a_src,
                                             const float* __restrict__ a_dst,
                                             const float* __restrict__ soff,
                                             const unsigned* __restrict__ adjT,
                                             float* __restrict__ out) {
    __shared__ float acc[32][256];                 // 32 KB
    __shared__ unsigned maskL[1024];               // 4 KB
    __shared__ __align__(16) float adL[32][4];     // 512 B
    __shared__ __align__(16) float soL[32][4];     // 512 B
    int bx = blockIdx.x;
    int c = bx & 7;
    int rem = bx >> 3;          // 0..63
    int jt = rem & 31;
    int tfh = rem >> 5;
    int cb = c << 10;
    int tid = threadIdx.x;

    for (int l = tid; l < 8192; l += 256) ((float*)acc)[l] = 0.f;
    for (int l = tid; l < 1024; l += 256)
        maskL[l] = adjT[((size_t)(cb + l))*32 + jt];
    if (tid < 32) {
        *(float4*)adL[tid] = *(const float4*)&a_dst[(size_t)(cb + jt*32 + tid)*4];
        *(float4*)soL[tid] = *(const float4*)&soff [(size_t)(cb + jt*32 + tid)*4];
    }
    __syncthreads();

    const unsigned short* pgb = Pg + (size_t)cb*2048 + (size_t)(tfh*256 + tid)*4;
    for (int i = 0; i < 1024; ++i) {
        unsigned mask = maskL[i];          // LDS broadcast, uniform branch
        if (!mask) continue;
        uint2 pr = *(const uint2*)(pgb + (size_t)i*2048);
        float4 as = *(const float4*)&a_src[(size_t)(cb + i)*4];
        float pv0 = bf2f((unsigned short)(pr.x & 0xffffu));
        float pv1 = bf2f((unsigned short)(pr.x >> 16));
        float pv2 = bf2f((unsigned short)(pr.y & 0xffffu));
        float pv3 = bf2f((unsigned short)(pr.y >> 16));
        do {
            int jl = __ffs(mask) - 1; mask &= mask - 1;
            float4 ad = *(const float4*)adL[jl];
            float4 so = *(const float4*)soL[jl];
            float z0 = as.x + ad.x; z0 = (z0 < 0.f) ? 0.2f*z0 : z0;
            float z1 = as.y + ad.y; z1 = (z1 < 0.f) ? 0.2f*z1 : z1;
            float z2 = as.z + ad.z; z2 = (z2 < 0.f) ? 0.2f*z2 : z2;
            float z3 = as.w + ad.w; z3 = (z3 < 0.f) ? 0.2f*z3 : z3;
            float dot = __expf(z0 - so.x)*pv0 + __expf(z1 - so.y)*pv1
                      + __expf(z2 - so.z)*pv2 + __expf(z3 - so.w)*pv3;
            acc[jl][tid] += dot;
        } while (mask);
    }
    __syncthreads();

    #pragma unroll 4
    for (int jl = 0; jl < 32; ++jl) {
        int j = jt*32 + jl;
        __builtin_nontemporal_store(acc[jl][tid]*0.25f,
            &out[(size_t)(cb + j)*512 + tfh*256 + tid]);
    }
}

// ---------------------------------------------------------------------------
extern "C" void kernel_launch(void* const* d_in, const int* in_sizes, int n_in,
                              void* d_out, int out_size, void* d_ws, size_t ws_size,
                              hipStream_t stream) {
    const int*   ei   = (const int*)d_in[0];
    const float* nf   = (const float*)d_in[1];
    const float* fc   = (const float*)d_in[2];
    const float* avs  = (const float*)d_in[3];
    const float* avd  = (const float*)d_in[4];

    float* out      = (float*)d_out;
    float* attn_out = out + OUT_ELEMS;

    char* ws = (char*)d_ws;
    unsigned short* Pg      = (unsigned short*)(ws + PG_OFF);
    float*          a_src_w = (float*)(ws + ASRC_OFF);
    float*          a_dst_w = (float*)(ws + ADST_OFF);
    float*          soff_w  = (float*)(ws + SOFF_OFF);
    unsigned*       adjw    = (unsigned*)(ws + ADJ_OFF);
    unsigned*       adjTw   = (unsigned*)(ws + ADJT_OFF);
    int*            degw    = (int*)(ws + DEG_OFF);
    unsigned short* listw   = (unsigned short*)(ws + LIST_OFF);
    unsigned short* fcTw    = (unsigned short*)(ws + FCT_OFF);

    k0_prep <<<162, 256, 0, stream>>>(fc, fcTw, (uint4*)(ws + ADJ_OFF));
    k1_mfma <<<9728, 256, 0, stream>>>(nf, fcTw, avs, avd, Pg, a_src_w, a_dst_w,
                                       ei, adjw, adjTw, degw, listw,
                                       (u32x4*)attn_out);
    k2_soft <<<2048, 256, 0, stream>>>(a_src_w, a_dst_w, degw, listw,
                                       soff_w, attn_out);
    k3_pv   <<<512, 256, 0, stream>>>(Pg, a_src_w, a_dst_w, soff_w, adjTw, out);
}

// Round 14
// 130.157 us; speedup vs baseline: 2.1821x; 2.1821x over previous
//
#include <hip/hip_runtime.h>

typedef short  bf16x8 __attribute__((ext_vector_type(8)));
typedef float  f32x4  __attribute__((ext_vector_type(4)));
typedef unsigned u32x4 __attribute__((ext_vector_type(4)));

#define CC 8
#define NN 1024
#define TT 8
#define II 64
#define HH 4
#define FF 64
#define EE (CC*NN*16)          // 131072 edges
#define KK 256                 // F*H
#define MAXD 64                // CSR slot cap (P(indeg>64)≈0 at λ=16)
#define ENTCAP 1032            // per-window entry cap (avg ~510)

static const size_t OUT_ELEMS  = (size_t)CC*NN*TT*FF;     // 4,194,304
static const size_t ATTN_ELEMS = (size_t)CC*NN*NN*HH;     // 33,554,432

// ws layout (bytes); ADJ..DEG zeroed as one 2,129,920 B range (130 x 16 KB)
static const size_t PG_OFF   = 0;                          // Pg bf16 33,554,432
static const size_t ASRC_OFF = 33554432;                   // a_src f32 131,072
static const size_t ADST_OFF = ASRC_OFF + 131072;          // a_dst f32 131,072
static const size_t SOFF_OFF = ADST_OFF + 131072;          // soff  f32 131,072
static const size_t ADJ_OFF  = SOFF_OFF + 131072;          // adj bitset 1,048,576
static const size_t ADJT_OFF = ADJ_OFF + 1048576;          // adjT bitset 1,048,576
static const size_t DEG_OFF  = ADJT_OFF + 1048576;         // deg i32 32,768
static const size_t LIST_OFF = DEG_OFF + 32768;            // lists u16 1,048,576
static const size_t FCT_OFF  = LIST_OFF + 1048576;         // fcT bf16 262,144

static __device__ inline unsigned short f2bf(float x) {
    union { float f; unsigned u; } q; q.f = x;
    unsigned r = q.u + 0x7fffu + ((q.u >> 16) & 1u);   // RNE
    return (unsigned short)(r >> 16);
}
static __device__ inline float bf2f(unsigned short u) {
    return __uint_as_float(((unsigned)u) << 16);
}

// ---------------------------------------------------------------------------
// K0: zero adj+adjT+deg (130 x 16 KB) + fc->fcT transpose (32 blocks)
// ---------------------------------------------------------------------------
__global__ __launch_bounds__(256) void k0_prep(const float* __restrict__ fc,
                                               unsigned short* __restrict__ fcT,
                                               uint4* __restrict__ zbase) {
    int bx = blockIdx.x;
    int tid = threadIdx.x;
    if (bx < 130) {
        uint4 z = make_uint4(0u, 0u, 0u, 0u);
        uint4* p = zbase + (size_t)bx*1024;
        #pragma unroll
        for (int r = 0; r < 4; ++r) p[r*256 + tid] = z;
    } else {
        int b = bx - 130;                // 0..31
        int t = b >> 2, ib = (b & 3) << 4;
        __shared__ unsigned short ls[256][17];
        #pragma unroll
        for (int r = 0; r < 16; ++r)
            ls[tid][r] = f2bf(fc[(size_t)(t*64 + ib + r)*KK + tid]);  // coalesced
        __syncthreads();
        int ii = tid & 15, k0 = tid >> 4;
        #pragma unroll
        for (int it = 0; it < 16; ++it) {
            int k = it*16 + k0;
            fcT[(size_t)t*16384 + (size_t)k*64 + ib + ii] = ls[k][ii];
        }
    }
}

// ---------------------------------------------------------------------------
// K1 (fused): [0,1024) MFMA projection+logits; [1024,1536) CSR + adjT build;
// [1536,9728) NT dense zero-fill of attn output.
// ---------------------------------------------------------------------------
__global__ __launch_bounds__(256) void k1_mfma(const float* __restrict__ nf,
                                               const unsigned short* __restrict__ fcT,
                                               const float* __restrict__ avs,
                                               const float* __restrict__ avd,
                                               unsigned short* __restrict__ Pg,
                                               float* __restrict__ a_src,
                                               float* __restrict__ a_dst,
                                               const int* __restrict__ ei,
                                               unsigned* __restrict__ adj,
                                               unsigned* __restrict__ adjT,
                                               int* __restrict__ deg,
                                               unsigned short* __restrict__ lists,
                                               u32x4* __restrict__ attnz) {
    int bxg = blockIdx.x;
    int tid = threadIdx.x;

    if (bxg >= 1536) {                   // ---- attn zero-fill: 8192 x 16 KB
        u32x4 z = (u32x4)(0u);
        u32x4* p = attnz + (size_t)(bxg - 1536)*1024;
        #pragma unroll
        for (int r = 0; r < 4; ++r)
            __builtin_nontemporal_store(z, &p[r*256 + tid]);
        return;
    }
    if (bxg >= 1024) {                   // ---- CSR adjacency + adjT: 512 blocks
        int e = (bxg - 1024)*256 + tid;
        int s = ei[e];
        int d = ei[EE + e];
        int c = s >> 10, i = s & 1023, j = d & 1023;
        int cj = (c << 10) + j;
        atomicOr(&adjT[((size_t)((c << 10) + i))*32 + (j >> 5)], 1u << (j & 31));
        unsigned bit = 1u << (i & 31);
        unsigned old = atomicOr(&adj[(size_t)cj*32 + (i >> 5)], bit);
        if (!(old & bit)) {              // first inserter of this (i,j)
            int pos = atomicAdd(&deg[cj], 1);
            if (pos < MAXD) lists[(size_t)cj*MAXD + pos] = (unsigned short)i;
        }
        return;
    }

    // ---- MFMA projection (blocks 0..1023); c = bx&7 keeps XCD alignment
    __shared__ unsigned short stg[8*2048];
    __shared__ float avsL[2048];
    __shared__ float avdL[2048];
    int bx = bxg;
    int c = bx & 7, t = (bx >> 3) & 7, tile = bx >> 6;
    int w = tid >> 6, lane = tid & 63;
    int col = lane & 15, g = lane >> 4;

    for (int l = tid; l < 2048; l += 256) {
        int t2 = l & 7, cl = (l >> 3) & 15, ctl = (l >> 7) & 3, h = l >> 9;
        int si = h*512 + t2*64 + ctl*16 + cl;
        avsL[l] = avs[si];
        avdL[l] = avd[si];
    }

    int row = tile*64 + w*16 + col;
    const float* ap = nf + ((size_t)(c*NN + row)*TT + t)*II + g*8;
    bf16x8 afr[2];
    #pragma unroll
    for (int ks = 0; ks < 2; ++ks) {
        float4 x = *(const float4*)(ap + ks*32);
        float4 y = *(const float4*)(ap + ks*32 + 4);
        afr[ks][0] = (short)f2bf(x.x); afr[ks][1] = (short)f2bf(x.y);
        afr[ks][2] = (short)f2bf(x.z); afr[ks][3] = (short)f2bf(x.w);
        afr[ks][4] = (short)f2bf(y.x); afr[ks][5] = (short)f2bf(y.y);
        afr[ks][6] = (short)f2bf(y.z); afr[ks][7] = (short)f2bf(y.w);
    }

    const unsigned short* bp = fcT + (size_t)t*256*64 + col*64 + g*8;
    f32x4 acc[16];
    #pragma unroll
    for (int ct = 0; ct < 16; ++ct) {
        bf16x8 b0 = *(const bf16x8*)(bp + (size_t)ct*16*64);
        bf16x8 b1 = *(const bf16x8*)(bp + (size_t)ct*16*64 + 32);
        f32x4 a; a[0] = 0.f; a[1] = 0.f; a[2] = 0.f; a[3] = 0.f;
        a = __builtin_amdgcn_mfma_f32_16x16x32_bf16(afr[0], b0, a, 0, 0, 0);
        a = __builtin_amdgcn_mfma_f32_16x16x32_bf16(afr[1], b1, a, 0, 0, 0);
        acc[ct] = a;
    }

    int nd = w*2 + (g >> 1);
    int t2b = (g & 1)*4;
    #pragma unroll
    for (int ctl = 0; ctl < 4; ++ctl) {
        int f2 = ctl*16 + col;
        #pragma unroll
        for (int v = 0; v < 4; ++v) {
            unsigned u0 = (unsigned)f2bf(acc[ctl     ][v]) | ((unsigned)f2bf(acc[ 4+ctl][v]) << 16);
            unsigned u1 = (unsigned)f2bf(acc[ 8+ctl][v]) | ((unsigned)f2bf(acc[12+ctl][v]) << 16);
            *(uint2*)&stg[nd*2048 + (t2b + v)*256 + f2*4] = make_uint2(u0, u1);
        }
    }

    __syncthreads();

    #pragma unroll
    for (int h = 0; h < 4; ++h) {
        float s = 0.f, d = 0.f;
        #pragma unroll
        for (int ctl = 0; ctl < 4; ++ctl) {
            float4 wS = *(const float4*)&avsL[((h*4 + ctl)*16 + col)*8 + t2b];
            float4 wD = *(const float4*)&avdL[((h*4 + ctl)*16 + col)*8 + t2b];
            f32x4 a = acc[h*4 + ctl];
            s += a[0]*wS.x + a[1]*wS.y + a[2]*wS.z + a[3]*wS.w;
            d += a[0]*wD.x + a[1]*wD.y + a[2]*wD.z + a[3]*wD.w;
        }
        #pragma unroll
        for (int m = 1; m <= 16; m <<= 1) { s += __shfl_xor(s, m); d += __shfl_xor(d, m); }
        if ((lane & 31) == 0) {
            int n2 = t*128 + tile*8 + w*2 + (lane >> 5);
            a_src[(size_t)(c*NN + n2)*HH + h] = s;
            a_dst[(size_t)(c*NN + n2)*HH + h] = d;
        }
    }

    {
        size_t gb = ((size_t)(c*NN) + t*128 + tile*8)*2048;
        const uint4* s4 = (const uint4*)stg;
        uint4* g4 = (uint4*)(Pg + gb);
        for (int l = tid; l < 2048; l += 256) g4[l] = s4[l];
    }
}

// ---------------------------------------------------------------------------
// K2: wave-per-dst softmax from CSR (no barriers): writes soff + attn scatter
// ---------------------------------------------------------------------------
__global__ __launch_bounds__(256) void k2_soft(const float* __restrict__ a_src,
                                               const float* __restrict__ a_dst,
                                               const int* __restrict__ deg,
                                               const unsigned short* __restrict__ lists,
                                               float* __restrict__ soff,
                                               float* __restrict__ attn_out) {
    int wid = threadIdx.x >> 6, lane = threadIdx.x & 63;
    int bx = blockIdx.x;
    int c = bx & 7;
    int j = (bx >> 3)*4 + wid;
    int cb = c << 10, cj = cb + j;

    int n = deg[cj]; if (n > MAXD) n = MAXD;
    bool valid = lane < n;
    int i = valid ? (int)lists[(size_t)cj*MAXD + lane] : 0;

    float4 ad = *(const float4*)&a_dst[(size_t)cj*4];
    float4 z4 = make_float4(-1e30f, -1e30f, -1e30f, -1e30f);
    if (valid) {
        float4 as = *(const float4*)&a_src[(size_t)(cb + i)*4];
        z4.x = as.x + ad.x; z4.x = (z4.x < 0.f) ? 0.2f*z4.x : z4.x;
        z4.y = as.y + ad.y; z4.y = (z4.y < 0.f) ? 0.2f*z4.y : z4.y;
        z4.z = as.z + ad.z; z4.z = (z4.z < 0.f) ? 0.2f*z4.z : z4.z;
        z4.w = as.w + ad.w; z4.w = (z4.w < 0.f) ? 0.2f*z4.w : z4.w;
    }
    float4 mx = z4;
    #pragma unroll
    for (int mm = 32; mm; mm >>= 1) {
        mx.x = fmaxf(mx.x, __shfl_xor(mx.x, mm));
        mx.y = fmaxf(mx.y, __shfl_xor(mx.y, mm));
        mx.z = fmaxf(mx.z, __shfl_xor(mx.z, mm));
        mx.w = fmaxf(mx.w, __shfl_xor(mx.w, mm));
    }
    float4 ez = make_float4(0.f, 0.f, 0.f, 0.f);
    if (valid) {
        ez.x = __expf(z4.x - mx.x);
        ez.y = __expf(z4.y - mx.y);
        ez.z = __expf(z4.z - mx.z);
        ez.w = __expf(z4.w - mx.w);
    }
    float4 sm = ez;
    #pragma unroll
    for (int mm = 32; mm; mm >>= 1) {
        sm.x += __shfl_xor(sm.x, mm);
        sm.y += __shfl_xor(sm.y, mm);
        sm.z += __shfl_xor(sm.z, mm);
        sm.w += __shfl_xor(sm.w, mm);
    }
    if (valid) {
        f32x4 sv;
        sv[0] = ez.x / sm.x; sv[1] = ez.y / sm.y;
        sv[2] = ez.z / sm.z; sv[3] = ez.w / sm.w;
        __builtin_nontemporal_store(sv,
            (f32x4*)&attn_out[((size_t)(cb + i)*NN + j)*4]);
    }
    if (lane == 0 && n > 0) {
        f32x4 so;
        so[0] = mx.x + __logf(sm.x); so[1] = mx.y + __logf(sm.y);
        so[2] = mx.z + __logf(sm.z); so[3] = mx.w + __logf(sm.w);
        *(f32x4*)&soff[(size_t)cj*4] = so;
    }
}

// ---------------------------------------------------------------------------
// K3: streaming PV, entry-list form. grid = (c, 32-j window, tf-half) = 512.
// Phase A: deterministic i-ordered entry build (shfl-scan, no atomics).
// Phase B: per-entry weights computed ONCE (exp count /256 vs R13).
// Phase C: stream entries — coalesced uint2 row load + 4 FMA + LDS acc.
// ---------------------------------------------------------------------------
__global__ __launch_bounds__(256) void k3_pv(const unsigned short* __restrict__ Pg,
                                             const float* __restrict__ a_src,
                                             const float* __restrict__ a_dst,
                                             const float* __restrict__ soff,
                                             const unsigned* __restrict__ adjT,
                                             float* __restrict__ out) {
    __shared__ float acc[32][256];                 // 32 KB
    __shared__ unsigned maskL[1024];               // 4 KB
    __shared__ unsigned EI[ENTCAP];                // 4.1 KB
    __shared__ __align__(16) float wTab[ENTCAP][4];// 16.5 KB
    __shared__ __align__(16) float adL[32][4];     // 512 B
    __shared__ __align__(16) float soL[32][4];     // 512 B
    __shared__ int wtot[4];
    int bx = blockIdx.x;
    int c = bx & 7;
    int rem = bx >> 3;          // 0..63
    int jt = rem & 31;
    int tfh = rem >> 5;
    int cb = c << 10;
    int tid = threadIdx.x;

    for (int l = tid; l < 8192; l += 256) ((float*)acc)[l] = 0.f;
    for (int l = tid; l < 1024; l += 256)
        maskL[l] = adjT[((size_t)(cb + l))*32 + jt];
    if (tid < 32) {
        *(float4*)adL[tid] = *(const float4*)&a_dst[(size_t)(cb + jt*32 + tid)*4];
        *(float4*)soL[tid] = *(const float4*)&soff [(size_t)(cb + jt*32 + tid)*4];
    }
    __syncthreads();

    // ---- Phase A: i-ordered entry list via prefix scan
    int i0 = tid*4;
    unsigned m0 = maskL[i0], m1 = maskL[i0+1], m2 = maskL[i0+2], m3 = maskL[i0+3];
    int lc = __popc(m0) + __popc(m1) + __popc(m2) + __popc(m3);
    int ln = tid & 63, wv = tid >> 6;
    int x = lc;
    #pragma unroll
    for (int s = 1; s < 64; s <<= 1) {
        int t = __shfl_up(x, s);
        if (ln >= s) x += t;
    }
    if (ln == 63) wtot[wv] = x;
    __syncthreads();
    int off = x - lc;
    #pragma unroll
    for (int w = 0; w < 4; ++w) if (w < wv) off += wtot[w];
    int cnt = wtot[0] + wtot[1] + wtot[2] + wtot[3];
    if (cnt > ENTCAP - 8) cnt = ENTCAP - 8;
    int cnt4 = (cnt + 3) & ~3;
    #pragma unroll
    for (int k = 0; k < 4; ++k) {
        int i = i0 + k;
        unsigned mk = (k == 0) ? m0 : (k == 1) ? m1 : (k == 2) ? m2 : m3;
        while (mk) {
            int jl = __ffs(mk) - 1; mk &= mk - 1;
            if (off < ENTCAP) EI[off] = (unsigned)((i << 5) | jl);
            ++off;
        }
    }
    __syncthreads();

    // ---- Phase B: weights once per entry
    for (int e = tid; e < cnt4; e += 256) {
        if (e < cnt) {
            unsigned en = EI[e];
            int i = en >> 5, jl = en & 31;
            float4 as = *(const float4*)&a_src[(size_t)(cb + i)*4];
            float4 ad = *(const float4*)adL[jl];
            float4 so = *(const float4*)soL[jl];
            float z0 = as.x + ad.x; z0 = (z0 < 0.f) ? 0.2f*z0 : z0;
            float z1 = as.y + ad.y; z1 = (z1 < 0.f) ? 0.2f*z1 : z1;
            float z2 = as.z + ad.z; z2 = (z2 < 0.f) ? 0.2f*z2 : z2;
            float z3 = as.w + ad.w; z3 = (z3 < 0.f) ? 0.2f*z3 : z3;
            f32x4 w4;
            w4[0] = __expf(z0 - so.x); w4[1] = __expf(z1 - so.y);
            w4[2] = __expf(z2 - so.z); w4[3] = __expf(z3 - so.w);
            *(f32x4*)wTab[e] = w4;
        } else {
            EI[e] = 0;
            *(f32x4*)wTab[e] = (f32x4)(0.f);
        }
    }
    __syncthreads();

    // ---- Phase C: stream entries, 4-deep
    const unsigned short* pgb = Pg + (size_t)cb*2048 + (size_t)(tfh*256 + tid)*4;
    for (int e0 = 0; e0 < cnt4; e0 += 4) {
        unsigned en0 = EI[e0], en1 = EI[e0+1], en2 = EI[e0+2], en3 = EI[e0+3];
        uint2 p0 = *(const uint2*)(pgb + (size_t)(en0 >> 5)*2048);
        uint2 p1 = *(const uint2*)(pgb + (size_t)(en1 >> 5)*2048);
        uint2 p2 = *(const uint2*)(pgb + (size_t)(en2 >> 5)*2048);
        uint2 p3 = *(const uint2*)(pgb + (size_t)(en3 >> 5)*2048);
        float4 w0 = *(const float4*)wTab[e0];
        float4 w1 = *(const float4*)wTab[e0+1];
        float4 w2 = *(const float4*)wTab[e0+2];
        float4 w3 = *(const float4*)wTab[e0+3];
        float d0 = w0.x*bf2f((unsigned short)(p0.x & 0xffffu))
                 + w0.y*bf2f((unsigned short)(p0.x >> 16))
                 + w0.z*bf2f((unsigned short)(p0.y & 0xffffu))
                 + w0.w*bf2f((unsigned short)(p0.y >> 16));
        float d1 = w1.x*bf2f((unsigned short)(p1.x & 0xffffu))
                 + w1.y*bf2f((unsigned short)(p1.x >> 16))
                 + w1.z*bf2f((unsigned short)(p1.y & 0xffffu))
                 + w1.w*bf2f((unsigned short)(p1.y >> 16));
        float d2 = w2.x*bf2f((unsigned short)(p2.x & 0xffffu))
                 + w2.y*bf2f((unsigned short)(p2.x >> 16))
                 + w2.z*bf2f((unsigned short)(p2.y & 0xffffu))
                 + w2.w*bf2f((unsigned short)(p2.y >> 16));
        float d3 = w3.x*bf2f((unsigned short)(p3.x & 0xffffu))
                 + w3.y*bf2f((unsigned short)(p3.x >> 16))
                 + w3.z*bf2f((unsigned short)(p3.y & 0xffffu))
                 + w3.w*bf2f((unsigned short)(p3.y >> 16));
        acc[en0 & 31][tid] += d0;
        acc[en1 & 31][tid] += d1;
        acc[en2 & 31][tid] += d2;
        acc[en3 & 31][tid] += d3;
    }
    __syncthreads();

    #pragma unroll 4
    for (int jl = 0; jl < 32; ++jl) {
        int j = jt*32 + jl;
        __builtin_nontemporal_store(acc[jl][tid]*0.25f,
            &out[(size_t)(cb + j)*512 + tfh*256 + tid]);
    }
}

// ---------------------------------------------------------------------------
extern "C" void kernel_launch(void* const* d_in, const int* in_sizes, int n_in,
                              void* d_out, int out_size, void* d_ws, size_t ws_size,
                              hipStream_t stream) {
    const int*   ei   = (const int*)d_in[0];
    const float* nf   = (const float*)d_in[1];
    const float* fc   = (const float*)d_in[2];
    const float* avs  = (const float*)d_in[3];
    const float* avd  = (const float*)d_in[4];

    float* out      = (float*)d_out;
    float* attn_out = out + OUT_ELEMS;

    char* ws = (char*)d_ws;
    unsigned short* Pg      = (unsigned short*)(ws + PG_OFF);
    float*          a_src_w = (float*)(ws + ASRC_OFF);
    float*          a_dst_w = (float*)(ws + ADST_OFF);
    float*          soff_w  = (float*)(ws + SOFF_OFF);
    unsigned*       adjw    = (unsigned*)(ws + ADJ_OFF);
    unsigned*       adjTw   = (unsigned*)(ws + ADJT_OFF);
    int*            degw    = (int*)(ws + DEG_OFF);
    unsigned short* listw   = (unsigned short*)(ws + LIST_OFF);
    unsigned short* fcTw    = (unsigned short*)(ws + FCT_OFF);

    k0_prep <<<162, 256, 0, stream>>>(fc, fcTw, (uint4*)(ws + ADJ_OFF));
    k1_mfma <<<9728, 256, 0, stream>>>(nf, fcTw, avs, avd, Pg, a_src_w, a_dst_w,
                                       ei, adjw, adjTw, degw, listw,
                                       (u32x4*)attn_out);
    k2_soft <<<2048, 256, 0, stream>>>(a_src_w, a_dst_w, degw, listw,
                                       soff_w, attn_out);
    k3_pv   <<<512, 256, 0, stream>>>(Pg, a_src_w, a_dst_w, soff_w, adjTw, out);
}

// Round 15
// 98.422 us; speedup vs baseline: 2.8857x; 1.3224x over previous
//
#include <hip/hip_runtime.h>

typedef short  bf16x8 __attribute__((ext_vector_type(8)));
typedef float  f32x4  __attribute__((ext_vector_type(4)));
typedef unsigned u32x4 __attribute__((ext_vector_type(4)));

#define CC 8
#define NN 1024
#define TT 8
#define II 64
#define HH 4
#define FF 64
#define EE (CC*NN*16)          // 131072 edges
#define KK 256                 // F*H
#define MAXD 64                // CSR slot cap (P(indeg>64)≈0 at λ=16)

static const size_t OUT_ELEMS  = (size_t)CC*NN*TT*FF;     // 4,194,304
static const size_t ATTN_ELEMS = (size_t)CC*NN*NN*HH;     // 33,554,432

// ws layout (bytes)
static const size_t PG_OFF   = 0;                          // Pg bf16 33,554,432
static const size_t ASRC_OFF = 33554432;                   // a_src f32 131,072
static const size_t ADST_OFF = ASRC_OFF + 131072;          // a_dst f32 131,072
static const size_t ADJ_OFF  = ADST_OFF + 131072;          // adj bitset 1,048,576
static const size_t DEG_OFF  = ADJ_OFF + 1048576;          // deg i32 32,768
static const size_t LIST_OFF = DEG_OFF + 32768;            // lists u16 1,048,576
static const size_t FCT_OFF  = LIST_OFF + 1048576;         // fcT bf16 262,144

static __device__ inline unsigned short f2bf(float x) {
    union { float f; unsigned u; } q; q.f = x;
    unsigned r = q.u + 0x7fffu + ((q.u >> 16) & 1u);   // RNE
    return (unsigned short)(r >> 16);
}
static __device__ inline float bf2f(unsigned short u) {
    return __uint_as_float(((unsigned)u) << 16);
}

// ---------------------------------------------------------------------------
// K0: zero adj bitset + deg counters (66 x 16 KB) + fc->fcT transpose
// ---------------------------------------------------------------------------
__global__ __launch_bounds__(256) void k0_prep(const float* __restrict__ fc,
                                               unsigned short* __restrict__ fcT,
                                               uint4* __restrict__ zbase) {
    int bx = blockIdx.x;
    int tid = threadIdx.x;
    if (bx < 66) {
        uint4 z = make_uint4(0u, 0u, 0u, 0u);
        uint4* p = zbase + (size_t)bx*1024;
        #pragma unroll
        for (int r = 0; r < 4; ++r) p[r*256 + tid] = z;
    } else {
        int b = bx - 66;                 // 0..31
        int t = b >> 2, ib = (b & 3) << 4;
        __shared__ unsigned short ls[256][17];   // [k][i'] pad 17
        #pragma unroll
        for (int r = 0; r < 16; ++r)
            ls[tid][r] = f2bf(fc[(size_t)(t*64 + ib + r)*KK + tid]);  // coalesced
        __syncthreads();
        int ii = tid & 15, k0 = tid >> 4;
        #pragma unroll
        for (int it = 0; it < 16; ++it) {
            int k = it*16 + k0;
            fcT[(size_t)t*16384 + (size_t)k*64 + ib + ii] = ls[k][ii];
        }
    }
}

// ---------------------------------------------------------------------------
// K1 (fused, 80-block chunks: 8 MFMA | 64 fill | 4 CSR | 4 idle).
// 80 % 8 == 0 keeps MFMA global-index&7 == m&7 -> XCD pinning preserved,
// while fill blocks are co-resident with compute from t=0 (no fill tail).
// grid = 128*80 = 10240.
// ---------------------------------------------------------------------------
__global__ __launch_bounds__(256) void k1_mfma(const float* __restrict__ nf,
                                               const unsigned short* __restrict__ fcT,
                                               const float* __restrict__ avs,
                                               const float* __restrict__ avd,
                                               unsigned short* __restrict__ Pg,
                                               float* __restrict__ a_src,
                                               float* __restrict__ a_dst,
                                               const int* __restrict__ ei,
                                               unsigned* __restrict__ adj,
                                               int* __restrict__ deg,
                                               unsigned short* __restrict__ lists,
                                               u32x4* __restrict__ attnz) {
    int bxg = blockIdx.x;
    int tid = threadIdx.x;
    int q = bxg / 80;
    int r = bxg - q*80;

    if (r >= 76) return;                 // idle pad
    if (r >= 72) {                       // ---- CSR adjacency: 512 blocks
        int e = (q*4 + (r - 72))*256 + tid;
        int s = ei[e];
        int d = ei[EE + e];
        int c = s >> 10, i = s & 1023, j = d & 1023;
        int cj = (c << 10) + j;
        unsigned bit = 1u << (i & 31);
        unsigned old = atomicOr(&adj[(size_t)cj*32 + (i >> 5)], bit);
        if (!(old & bit)) {              // first inserter of this (i,j)
            int pos = atomicAdd(&deg[cj], 1);
            if (pos < MAXD) lists[(size_t)cj*MAXD + pos] = (unsigned short)i;
        }
        return;
    }
    if (r >= 8) {                        // ---- attn zero-fill: 8192 x 16 KB
        u32x4 z = (u32x4)(0u);
        u32x4* p = attnz + (size_t)(q*64 + (r - 8))*1024;
        #pragma unroll
        for (int rr = 0; rr < 4; ++rr)
            __builtin_nontemporal_store(z, &p[rr*256 + tid]);
        return;
    }

    // ---- MFMA projection: m = q*8 + r in [0,1024); c = m&7 == bxg&7
    __shared__ unsigned short stg[8*2048];     // 32 KB: 8 nodes x [t2][f2][h]
    __shared__ float avsL[2048];               // [h][ctl][col][t2]
    __shared__ float avdL[2048];
    int m = q*8 + r;
    int c = m & 7, t = (m >> 3) & 7, tile = m >> 6;
    int w = tid >> 6, lane = tid & 63;
    int col = lane & 15, g = lane >> 4;

    for (int l = tid; l < 2048; l += 256) {
        int t2 = l & 7, cl = (l >> 3) & 15, ctl = (l >> 7) & 3, h = l >> 9;
        int si = h*512 + t2*64 + ctl*16 + cl;
        avsL[l] = avs[si];
        avdL[l] = avd[si];
    }

    int row = tile*64 + w*16 + col;
    const float* ap = nf + ((size_t)(c*NN + row)*TT + t)*II + g*8;
    bf16x8 afr[2];
    #pragma unroll
    for (int ks = 0; ks < 2; ++ks) {
        float4 x = *(const float4*)(ap + ks*32);
        float4 y = *(const float4*)(ap + ks*32 + 4);
        afr[ks][0] = (short)f2bf(x.x); afr[ks][1] = (short)f2bf(x.y);
        afr[ks][2] = (short)f2bf(x.z); afr[ks][3] = (short)f2bf(x.w);
        afr[ks][4] = (short)f2bf(y.x); afr[ks][5] = (short)f2bf(y.y);
        afr[ks][6] = (short)f2bf(y.z); afr[ks][7] = (short)f2bf(y.w);
    }

    const unsigned short* bp = fcT + (size_t)t*256*64 + col*64 + g*8;
    f32x4 acc[16];
    #pragma unroll
    for (int ct = 0; ct < 16; ++ct) {
        bf16x8 b0 = *(const bf16x8*)(bp + (size_t)ct*16*64);
        bf16x8 b1 = *(const bf16x8*)(bp + (size_t)ct*16*64 + 32);
        f32x4 a; a[0] = 0.f; a[1] = 0.f; a[2] = 0.f; a[3] = 0.f;
        a = __builtin_amdgcn_mfma_f32_16x16x32_bf16(afr[0], b0, a, 0, 0, 0);
        a = __builtin_amdgcn_mfma_f32_16x16x32_bf16(afr[1], b1, a, 0, 0, 0);
        acc[ct] = a;
    }

    int nd = w*2 + (g >> 1);
    int t2b = (g & 1)*4;
    #pragma unroll
    for (int ctl = 0; ctl < 4; ++ctl) {
        int f2 = ctl*16 + col;
        #pragma unroll
        for (int v = 0; v < 4; ++v) {
            unsigned u0 = (unsigned)f2bf(acc[ctl     ][v]) | ((unsigned)f2bf(acc[ 4+ctl][v]) << 16);
            unsigned u1 = (unsigned)f2bf(acc[ 8+ctl][v]) | ((unsigned)f2bf(acc[12+ctl][v]) << 16);
            *(uint2*)&stg[nd*2048 + (t2b + v)*256 + f2*4] = make_uint2(u0, u1);
        }
    }

    __syncthreads();

    #pragma unroll
    for (int h = 0; h < 4; ++h) {
        float s = 0.f, d = 0.f;
        #pragma unroll
        for (int ctl = 0; ctl < 4; ++ctl) {
            float4 wS = *(const float4*)&avsL[((h*4 + ctl)*16 + col)*8 + t2b];
            float4 wD = *(const float4*)&avdL[((h*4 + ctl)*16 + col)*8 + t2b];
            f32x4 a = acc[h*4 + ctl];
            s += a[0]*wS.x + a[1]*wS.y + a[2]*wS.z + a[3]*wS.w;
            d += a[0]*wD.x + a[1]*wD.y + a[2]*wD.z + a[3]*wD.w;
        }
        #pragma unroll
        for (int mm2 = 1; mm2 <= 16; mm2 <<= 1) { s += __shfl_xor(s, mm2); d += __shfl_xor(d, mm2); }
        if ((lane & 31) == 0) {
            int n2 = t*128 + tile*8 + w*2 + (lane >> 5);
            a_src[(size_t)(c*NN + n2)*HH + h] = s;
            a_dst[(size_t)(c*NN + n2)*HH + h] = d;
        }
    }

    {
        size_t gb = ((size_t)(c*NN) + t*128 + tile*8)*2048;
        const uint4* s4 = (const uint4*)stg;
        uint4* g4 = (uint4*)(Pg + gb);
        for (int l = tid; l < 2048; l += 256) g4[l] = s4[l];
    }
}

static __device__ inline void fma8(uint4 pv, float4 wv, float& a0, float& a1) {
    a0 += wv.x*bf2f((unsigned short)(pv.x & 0xffffu))
        + wv.y*bf2f((unsigned short)(pv.x >> 16))
        + wv.z*bf2f((unsigned short)(pv.y & 0xffffu))
        + wv.w*bf2f((unsigned short)(pv.y >> 16));
    a1 += wv.x*bf2f((unsigned short)(pv.z & 0xffffu))
        + wv.y*bf2f((unsigned short)(pv.z >> 16))
        + wv.z*bf2f((unsigned short)(pv.w & 0xffffu))
        + wv.w*bf2f((unsigned short)(pv.w >> 16));
}

// ---------------------------------------------------------------------------
// K5 (R10 form): per-(c,j) CSR list load + softmax + attn nt-scatter
// + PV (uint4, 4-deep) + head-mean. grid = C*N, c = blockIdx&7, 256 threads
// ---------------------------------------------------------------------------
__global__ __launch_bounds__(256) void k5_attn(const unsigned short* __restrict__ Pg,
                                               const float* __restrict__ a_src,
                                               const float* __restrict__ a_dst,
                                               const int* __restrict__ deg,
                                               const unsigned short* __restrict__ lists,
                                               float* __restrict__ attn_out,
                                               float* __restrict__ out) {
    __shared__ unsigned short L[MAXD];
    __shared__ __align__(16) float attL[MAXD][4];    // [e][h]
    int bx = blockIdx.x;
    int c = bx & 7, j = bx >> 3;
    int cb = c << 10;
    int cj = cb + j;
    int tid = threadIdx.x;

    int n = deg[cj]; if (n > MAXD) n = MAXD;
    int nn = (n + 3) & ~3;

    if (tid < n) L[tid] = lists[(size_t)cj*MAXD + tid];
    // pad to multiple of 4 with zero-weight row-0 entries (4-deep PV)
    if (tid >= n && tid < nn) {
        L[tid] = 0;
        *(f32x4*)attL[tid] = (f32x4)(0.f);
    }
    __syncthreads();

    int h = tid >> 6, lane = tid & 63;
    float adv = a_dst[(size_t)cj*4 + h];

    float m = -1e30f;
    for (int e = lane; e < n; e += 64) {
        float z = a_src[(size_t)(cb + L[e])*4 + h] + adv;
        z = (z < 0.f) ? 0.2f*z : z;          // leaky relu
        attL[e][h] = z;
        m = fmaxf(m, z);
    }
    #pragma unroll
    for (int mm = 32; mm; mm >>= 1) m = fmaxf(m, __shfl_xor(m, mm));
    float ssum = 0.f;
    for (int e = lane; e < n; e += 64) {
        float ez = __expf(attL[e][h] - m);
        attL[e][h] = ez;
        ssum += ez;
    }
    #pragma unroll
    for (int mm = 32; mm; mm >>= 1) ssum += __shfl_xor(ssum, mm);
    float inv = (n > 0) ? 1.f / ssum : 0.f;
    for (int e = lane; e < n; e += 64) attL[e][h] *= inv;
    __syncthreads();

    // nt-scatter nonzero attn entries (bypass L2 — keep Pg resident)
    if (tid < n) {
        int i = L[tid];
        f32x4 sv = *(const f32x4*)attL[tid];
        __builtin_nontemporal_store(sv, (f32x4*)&attn_out[((size_t)(cb + i)*NN + j)*4]);
    }

    // PV, 4 independent row-loads in flight; thread owns tf pair {2tid, 2tid+1}
    float acc0 = 0.f, acc1 = 0.f, acc2 = 0.f, acc3 = 0.f;
    const unsigned short* pgBase = Pg + (size_t)cb*2048 + tid*8;
    for (int e0 = 0; e0 < nn; e0 += 4) {
        uint4 p0 = *(const uint4*)(pgBase + (size_t)L[e0+0]*2048);
        uint4 p1 = *(const uint4*)(pgBase + (size_t)L[e0+1]*2048);
        uint4 p2 = *(const uint4*)(pgBase + (size_t)L[e0+2]*2048);
        uint4 p3 = *(const uint4*)(pgBase + (size_t)L[e0+3]*2048);
        float4 w0 = *(const float4*)attL[e0+0];
        float4 w1 = *(const float4*)attL[e0+1];
        float4 w2 = *(const float4*)attL[e0+2];
        float4 w3 = *(const float4*)attL[e0+3];
        fma8(p0, w0, acc0, acc1);
        fma8(p1, w1, acc2, acc3);
        fma8(p2, w2, acc0, acc1);
        fma8(p3, w3, acc2, acc3);
    }
    float2 o = make_float2((acc0 + acc2)*0.25f, (acc1 + acc3)*0.25f);
    __builtin_nontemporal_store(o.x, &out[(size_t)cj*512 + tid*2]);
    __builtin_nontemporal_store(o.y, &out[(size_t)cj*512 + tid*2 + 1]);
}

// ---------------------------------------------------------------------------
extern "C" void kernel_launch(void* const* d_in, const int* in_sizes, int n_in,
                              void* d_out, int out_size, void* d_ws, size_t ws_size,
                              hipStream_t stream) {
    const int*   ei   = (const int*)d_in[0];
    const float* nf   = (const float*)d_in[1];
    const float* fc   = (const float*)d_in[2];
    const float* avs  = (const float*)d_in[3];
    const float* avd  = (const float*)d_in[4];

    float* out      = (float*)d_out;
    float* attn_out = out + OUT_ELEMS;

    char* ws = (char*)d_ws;
    unsigned short* Pg      = (unsigned short*)(ws + PG_OFF);
    float*          a_src_w = (float*)(ws + ASRC_OFF);
    float*          a_dst_w = (float*)(ws + ADST_OFF);
    unsigned*       adjw    = (unsigned*)(ws + ADJ_OFF);
    int*            degw    = (int*)(ws + DEG_OFF);
    unsigned short* listw   = (unsigned short*)(ws + LIST_OFF);
    unsigned short* fcTw    = (unsigned short*)(ws + FCT_OFF);

    k0_prep <<<98, 256, 0, stream>>>(fc, fcTw, (uint4*)(ws + ADJ_OFF));
    k1_mfma <<<10240, 256, 0, stream>>>(nf, fcTw, avs, avd, Pg, a_src_w, a_dst_w,
                                        ei, adjw, degw, listw, (u32x4*)attn_out);
    k5_attn <<<CC*NN, 256, 0, stream>>>(Pg, a_src_w, a_dst_w, degw, listw,
                                        attn_out, out);
}